// Round 2
// baseline (975.998 us; speedup 1.0000x reference)
//
#include <hip/hip_runtime.h>
#include <cstdint>
#include <cstddef>

typedef unsigned short u16;
typedef unsigned int   u32;
typedef _Float16       f16;
typedef u16  u16x4 __attribute__((ext_vector_type(4)));
typedef u16  u16x8 __attribute__((ext_vector_type(8)));
typedef f16  f16x8 __attribute__((ext_vector_type(8)));
typedef float f32x4 __attribute__((ext_vector_type(4)));

static __device__ __forceinline__ u16 f2h(float f){
  f16 h = (f16)f;
  return __builtin_bit_cast(u16, h);
}
static __device__ __forceinline__ float h2f(u16 b){
  f16 h = __builtin_bit_cast(f16, b);
  return (float)h;
}

// ---- transpose 4 weight matrices (fp32 in) -> fp16 out, K-contiguous ----
__global__ void transpose_weights(const float* __restrict__ lw, const float* __restrict__ w1,
                                  const float* __restrict__ w2, const float* __restrict__ w3,
                                  u16* __restrict__ lwT, u16* __restrict__ w1T,
                                  u16* __restrict__ w2T, u16* __restrict__ w3T,
                                  int G, int Gpad)
{
  __shared__ float t[32][33];
  int z = blockIdx.z;
  const float* in = (z==0)? lw : (z==1)? w1 : (z==2)? w2 : w3;
  u16* out        = (z==0)? lwT: (z==1)? w1T: (z==2)? w2T: w3T;
  int R   = (z==0)? G : 256;
  int ldo = (z==0)? Gpad : 256;
  int by = blockIdx.y, bx = blockIdx.x;
  if (by*32 >= R) return;
  int tid = threadIdx.x;
  #pragma unroll
  for (int k=0;k<4;k++){
    int p = tid + k*256; int r = p>>5, c = p&31;
    int gr = by*32 + r;
    t[r][c] = (gr < R) ? in[gr*256 + bx*32 + c] : 0.f;
  }
  __syncthreads();
  #pragma unroll
  for (int k=0;k<4;k++){
    int p = tid + k*256; int r = p>>5, c = p&31;
    int oc = by*32 + c;
    if (oc < R) out[(bx*32 + r)*ldo + oc] = f2h(t[c][r]);
  }
}

// ---- CSR build ----
__global__ void count_kernel(const int* __restrict__ dst, int* __restrict__ cnt, int E){
  int e = blockIdx.x*256 + threadIdx.x;
  if (e < E) atomicAdd(&cnt[dst[e]], 1);
}

__global__ void scan_reduce(const int* __restrict__ cnt, int* __restrict__ bsum, int N){
  __shared__ int s[256];
  int tid = threadIdx.x;
  int i = blockIdx.x*256 + tid;
  s[tid] = (i<N)? cnt[i] : 0;
  __syncthreads();
  for (int off=128; off>0; off>>=1){
    if (tid < off) s[tid] += s[tid+off];
    __syncthreads();
  }
  if (tid==0) bsum[blockIdx.x] = s[0];
}

__global__ void scan_offsets(const int* __restrict__ bsum, int* __restrict__ boff, int nb){
  __shared__ int s[256];
  int tid = threadIdx.x;
  int v = (tid<nb)? bsum[tid] : 0;
  s[tid] = v; __syncthreads();
  for (int off=1; off<256; off<<=1){
    int t = (tid>=off)? s[tid-off] : 0;
    __syncthreads();
    s[tid] += t;
    __syncthreads();
  }
  if (tid<nb) boff[tid] = s[tid]-v;
}

__global__ void scan_final(const int* __restrict__ cnt, const int* __restrict__ boff,
                           int* __restrict__ row_ptr, float* __restrict__ dinv, int N, int E){
  __shared__ int s[256];
  int tid = threadIdx.x;
  int i = blockIdx.x*256 + tid;
  int v = (i<N)? cnt[i] : 0;
  s[tid] = v; __syncthreads();
  for (int off=1; off<256; off<<=1){
    int t = (tid>=off)? s[tid-off] : 0;
    __syncthreads();
    s[tid] += t;
    __syncthreads();
  }
  if (i < N){
    row_ptr[i] = boff[blockIdx.x] + s[tid] - v;
    dinv[i] = rsqrtf((float)(v+1));
  }
  if (i == N-1) row_ptr[N] = E;
}

__global__ void scatter_kernel(const int* __restrict__ src, const int* __restrict__ dst,
                               const int* __restrict__ row_ptr, int* __restrict__ cursor,
                               int* __restrict__ colx, int E){
  int e = blockIdx.x*256 + threadIdx.x;
  if (e < E){
    int d = dst[e];
    int pos = atomicAdd(&cursor[d], 1);
    colx[row_ptr[d] + pos] = src[e];
  }
}

// ---- GEMM: C[M x 256] = A[M x lda(Ka valid)] @ BT[256 x Kpad]^T, fp16 MFMA ----
// XPATH: A is fp32, Ka possibly < Kpad (convert + mask). else A is fp16, lda==Kpad.
template<bool XPATH, bool ADD_BIAS>
__global__ __launch_bounds__(256) void gemm_bt(
    const void* __restrict__ Av, int lda, int Ka,
    const u16* __restrict__ BT, int Kpad,
    u16* __restrict__ C, const float* __restrict__ bias, int M)
{
  __shared__ u16 As[128*40];
  __shared__ u16 Bs[128*40];
  const int tid  = threadIdx.x;
  const int lane = tid & 63;
  const int quad = lane >> 4;
  const int l16  = lane & 15;
  const int wave = tid >> 6;
  const int wm = (wave >> 1) << 6;
  const int wn = (wave & 1) << 6;
  const int m0 = blockIdx.y << 7;
  const int n0 = blockIdx.x << 7;

  f32x4 acc[4][4];
  #pragma unroll
  for (int i=0;i<4;i++)
    #pragma unroll
    for (int j=0;j<4;j++) acc[i][j] = {0.f,0.f,0.f,0.f};

  for (int k0 = 0; k0 < Kpad; k0 += 32){
    if constexpr (XPATH){
      const float* A = (const float*)Av;
      #pragma unroll
      for (int c=0;c<8;c++){
        int p = tid + (c<<8);
        int row = p >> 4;
        int cp  = (p & 15) << 1;
        int gr = m0 + row, gc = k0 + cp;
        float vx = 0.f, vy = 0.f;
        if (gr < M && gc < Ka){
          float2 v = *(const float2*)(A + (size_t)gr*lda + gc);
          vx = v.x; vy = v.y;
        }
        u32 pk = (u32)f2h(vx) | ((u32)f2h(vy) << 16);
        *(u32*)(As + row*40 + cp) = pk;
      }
    } else {
      const u16* A = (const u16*)Av;
      #pragma unroll
      for (int c=0;c<2;c++){
        int p = tid + (c<<8);
        int row = p >> 2;
        int cp  = (p & 3) << 3;
        int gr = m0 + row;
        u16x8 v = {0,0,0,0,0,0,0,0};
        if (gr < M) v = *(const u16x8*)(A + (size_t)gr*lda + k0 + cp);
        *(u16x8*)(As + row*40 + cp) = v;
      }
    }
    #pragma unroll
    for (int c=0;c<2;c++){
      int p = tid + (c<<8);
      int row = p >> 2;
      int cp  = (p & 3) << 3;
      u16x8 v = *(const u16x8*)(BT + (size_t)(n0 + row)*Kpad + k0 + cp);
      *(u16x8*)(Bs + row*40 + cp) = v;
    }
    __syncthreads();

    f16x8 af[4], bfr[4];
    #pragma unroll
    for (int mt=0;mt<4;mt++)
      af[mt] = __builtin_bit_cast(f16x8, *(const u16x8*)(As + (wm + mt*16 + l16)*40 + quad*8));
    #pragma unroll
    for (int nt=0;nt<4;nt++)
      bfr[nt] = __builtin_bit_cast(f16x8, *(const u16x8*)(Bs + (wn + nt*16 + l16)*40 + quad*8));
    #pragma unroll
    for (int mt=0;mt<4;mt++)
      #pragma unroll
      for (int nt=0;nt<4;nt++)
        acc[mt][nt] = __builtin_amdgcn_mfma_f32_16x16x32_f16(af[mt], bfr[nt], acc[mt][nt], 0, 0, 0);
    __syncthreads();
  }

  #pragma unroll
  for (int mt=0;mt<4;mt++){
    #pragma unroll
    for (int nt=0;nt<4;nt++){
      int col = n0 + wn + nt*16 + l16;
      float bv = 0.f;
      if constexpr (ADD_BIAS) bv = bias[col];
      #pragma unroll
      for (int r=0;r<4;r++){
        int row = m0 + wm + mt*16 + quad*4 + r;
        if (row < M) C[(size_t)row*256 + col] = f2h(acc[mt][nt][r] + bv);
      }
    }
  }
}

// ---- GCN aggregation: H[i] = relu( sum_e dinv[s]*dinv[i]*XW[s] + dinv[i]^2*XW[i] + b ) ----
__global__ __launch_bounds__(256) void agg_kernel(
    const u16* __restrict__ XW, const float* __restrict__ bias,
    const float* __restrict__ dinv, const int* __restrict__ row_ptr,
    const int* __restrict__ colx, u16* __restrict__ H, int N)
{
  int wid = (blockIdx.x << 2) + (threadIdx.x >> 6);
  if (wid >= N) return;
  int lane = threadIdx.x & 63;
  int f = lane << 2;
  float di = dinv[wid];
  int e0 = row_ptr[wid], e1 = row_ptr[wid+1];
  float a0=0.f, a1=0.f, a2=0.f, a3=0.f;
  for (int e=e0; e<e1; e++){
    int s = colx[e];
    float w = dinv[s]*di;
    u16x4 xv = *(const u16x4*)(XW + (size_t)s*256 + f);
    a0 += w*h2f(xv[0]); a1 += w*h2f(xv[1]); a2 += w*h2f(xv[2]); a3 += w*h2f(xv[3]);
  }
  u16x4 xs = *(const u16x4*)(XW + (size_t)wid*256 + f);
  float wd = di*di;
  a0 += wd*h2f(xs[0]); a1 += wd*h2f(xs[1]); a2 += wd*h2f(xs[2]); a3 += wd*h2f(xs[3]);
  const float4 bb = *(const float4*)(bias + f);
  a0 = fmaxf(a0 + bb.x, 0.f);
  a1 = fmaxf(a1 + bb.y, 0.f);
  a2 = fmaxf(a2 + bb.z, 0.f);
  a3 = fmaxf(a3 + bb.w, 0.f);
  u16x4 o = { f2h(a0), f2h(a1), f2h(a2), f2h(a3) };
  *(u16x4*)(H + (size_t)wid*256 + f) = o;
}

// ---- BN stats over axis 0 ----
__global__ void bn_stats(const u16* __restrict__ H, float* __restrict__ bsum,
                         float* __restrict__ bsq, int N){
  int col = threadIdx.x;
  float s=0.f, q=0.f;
  for (int r=blockIdx.x; r<N; r+=gridDim.x){
    float v = h2f(H[(size_t)r*256 + col]);
    s += v; q += v*v;
  }
  atomicAdd(&bsum[col], s);
  atomicAdd(&bsq[col], q);
}

__global__ void bn_finalize(const float* __restrict__ bsum, const float* __restrict__ bsq,
                            const float* __restrict__ gamma, const float* __restrict__ beta,
                            float* __restrict__ scale, float* __restrict__ shift, int N){
  int c = threadIdx.x;
  float invN = 1.f/(float)N;
  float mu  = bsum[c]*invN;
  float var = bsq[c]*invN - mu*mu;
  float sc  = gamma[c] * rsqrtf(var + 1e-5f);
  scale[c] = sc;
  shift[c] = beta[c] - mu*sc;
}

// ---- BN-apply + relu + mlp2 + softmax ----
__global__ __launch_bounds__(256) void final_kernel(
    const u16* __restrict__ H, const float* __restrict__ scale, const float* __restrict__ shift,
    const float* __restrict__ W2, const float* __restrict__ b2, float* __restrict__ out, int N)
{
  __shared__ float W2s[256*20];
  __shared__ float scs[256];
  __shared__ float shs[256];
  __shared__ float b2s[20];
  int tid = threadIdx.x;
  for (int i=tid; i<5120; i+=256) W2s[i] = W2[i];
  scs[tid] = scale[tid];
  shs[tid] = shift[tid];
  if (tid < 20) b2s[tid] = b2[tid];
  __syncthreads();
  int r = blockIdx.x*256 + tid;
  if (r >= N) return;
  float l[20];
  #pragma unroll
  for (int c=0;c<20;c++) l[c] = b2s[c];
  const u16* hrow = H + (size_t)r*256;
  for (int j0=0;j0<256;j0+=8){
    u16x8 h8 = *(const u16x8*)(hrow + j0);
    #pragma unroll
    for (int t=0;t<8;t++){
      int j = j0+t;
      float a = fmaxf(fmaf(h2f(h8[t]), scs[j], shs[j]), 0.f);
      const float* wr = W2s + j*20;
      #pragma unroll
      for (int c=0;c<20;c++) l[c] = fmaf(a, wr[c], l[c]);
    }
  }
  float m = l[0];
  #pragma unroll
  for (int c=1;c<20;c++) m = fmaxf(m, l[c]);
  float ssum = 0.f;
  #pragma unroll
  for (int c=0;c<20;c++){ l[c] = __expf(l[c]-m); ssum += l[c]; }
  float inv = 1.f/ssum;
  float* orow = out + (size_t)r*20;
  #pragma unroll
  for (int c=0;c<20;c++) orow[c] = l[c]*inv;
}

extern "C" void kernel_launch(void* const* d_in, const int* in_sizes, int n_in,
                              void* d_out, int out_size, void* d_ws, size_t ws_size,
                              hipStream_t stream)
{
  (void)n_in; (void)out_size; (void)ws_size;
  const float* x     = (const float*)d_in[0];
  const int*   ei    = (const int*)d_in[1];
  const float* lin_w = (const float*)d_in[2];
  const float* c1w   = (const float*)d_in[3];
  const float* c1b   = (const float*)d_in[4];
  const float* c2w   = (const float*)d_in[5];
  const float* c2b   = (const float*)d_in[6];
  const float* m1w   = (const float*)d_in[7];
  const float* m1b   = (const float*)d_in[8];
  const float* gam   = (const float*)d_in[9];
  const float* bet   = (const float*)d_in[10];
  const float* m2w   = (const float*)d_in[11];
  const float* m2b   = (const float*)d_in[12];
  float* out = (float*)d_out;

  const int E = in_sizes[1]/2;
  const int G = in_sizes[2]/256;          // 1002
  const int N = in_sizes[0]/G;            // 50000
  const int Gpad = (G + 31) & ~31;        // 1024
  const int* srcI = ei;
  const int* dstI = ei + E;

  char* w = (char*)d_ws;
  auto alloc = [&](size_t bytes)->char*{
    char* p = w;
    w += (bytes + 255) & ~(size_t)255;
    return p;
  };
  u16* Ha    = (u16*)alloc((size_t)N*256*2);
  u16* Hb    = (u16*)alloc((size_t)N*256*2);
  u16* linT  = (u16*)alloc((size_t)256*Gpad*2);
  u16* w1T   = (u16*)alloc(256*256*2);
  u16* w2T   = (u16*)alloc(256*256*2);
  u16* w3T   = (u16*)alloc(256*256*2);
  int* cnt    = (int*)alloc((size_t)N*4);
  int* cursor = (int*)alloc((size_t)N*4);
  int* rowp   = (int*)alloc((size_t)(N+1)*4);
  int* colx   = (int*)alloc((size_t)E*4);
  float* dinv = (float*)alloc((size_t)N*4);
  int* bsum   = (int*)alloc(1024);
  int* boff   = (int*)alloc(1024);
  float* bnsum= (float*)alloc(1024);
  float* bnsq = (float*)alloc(1024);
  float* scl  = (float*)alloc(1024);
  float* shf  = (float*)alloc(1024);

  hipMemsetAsync(cnt,    0, (size_t)N*4, stream);
  hipMemsetAsync(cursor, 0, (size_t)N*4, stream);
  hipMemsetAsync(bnsum,  0, 2048, stream);               // bnsum + bnsq (contiguous)
  hipMemsetAsync(linT,   0, (size_t)256*Gpad*2, stream); // zero K-pad region

  const int NB = (N + 255)/256;

  transpose_weights<<<dim3(8, Gpad>>5, 4), 256, 0, stream>>>(
      lin_w, c1w, c2w, m1w, linT, w1T, w2T, w3T, G, Gpad);
  count_kernel  <<<dim3((E+255)/256), 256, 0, stream>>>(dstI, cnt, E);
  scan_reduce   <<<dim3(NB), 256, 0, stream>>>(cnt, bsum, N);
  scan_offsets  <<<dim3(1),  256, 0, stream>>>(bsum, boff, NB);
  scan_final    <<<dim3(NB), 256, 0, stream>>>(cnt, boff, rowp, dinv, N, E);
  scatter_kernel<<<dim3((E+255)/256), 256, 0, stream>>>(srcI, dstI, rowp, cursor, colx, E);

  dim3 ggrid(2, (N+127)/128);
  gemm_bt<true,  false><<<ggrid, 256, 0, stream>>>(x,  G,   G,   linT, Gpad, Ha, nullptr, N);
  gemm_bt<false, false><<<ggrid, 256, 0, stream>>>(Ha, 256, 256, w1T,  256,  Hb, nullptr, N);
  agg_kernel<<<dim3((N+3)/4), 256, 0, stream>>>(Hb, c1b, dinv, rowp, colx, Ha, N);
  gemm_bt<false, false><<<ggrid, 256, 0, stream>>>(Ha, 256, 256, w2T,  256,  Hb, nullptr, N);
  agg_kernel<<<dim3((N+3)/4), 256, 0, stream>>>(Hb, c2b, dinv, rowp, colx, Ha, N);
  gemm_bt<false, true ><<<ggrid, 256, 0, stream>>>(Ha, 256, 256, w3T,  256,  Hb, m1b, N);
  bn_stats   <<<dim3(256), 256, 0, stream>>>(Hb, bnsum, bnsq, N);
  bn_finalize<<<dim3(1),   256, 0, stream>>>(bnsum, bnsq, gam, bet, scl, shf, N);
  final_kernel<<<dim3(NB), 256, 0, stream>>>(Hb, scl, shf, m2w, m2b, out, N);
}

// Round 3
// 731.308 us; speedup vs baseline: 1.3346x; 1.3346x over previous
//
#include <hip/hip_runtime.h>
#include <cstdint>
#include <cstddef>

typedef unsigned short u16;
typedef unsigned int   u32;
typedef _Float16       f16;
typedef u16  u16x4 __attribute__((ext_vector_type(4)));
typedef u16  u16x8 __attribute__((ext_vector_type(8)));
typedef f16  f16x8 __attribute__((ext_vector_type(8)));
typedef f16  f16x2 __attribute__((ext_vector_type(2)));
typedef float f32x4 __attribute__((ext_vector_type(4)));

static __device__ __forceinline__ u16 f2h(float f){
  f16 h = (f16)f;
  return __builtin_bit_cast(u16, h);
}
static __device__ __forceinline__ float h2f(u16 b){
  f16 h = __builtin_bit_cast(f16, b);
  return (float)h;
}

// async global->LDS, 16B per lane. lds base must be wave-uniform; HW adds lane*16.
static __device__ __forceinline__ void async16(void* lds, const void* g){
  __builtin_amdgcn_global_load_lds(
      (const __attribute__((address_space(1))) u32*)g,
      (__attribute__((address_space(3))) u32*)lds, 16, 0, 0);
}

// ---- transpose 4 weight matrices (fp32 in) -> fp16 out, K-contiguous ----
__global__ void transpose_weights(const float* __restrict__ lw, const float* __restrict__ w1,
                                  const float* __restrict__ w2, const float* __restrict__ w3,
                                  u16* __restrict__ lwT, u16* __restrict__ w1T,
                                  u16* __restrict__ w2T, u16* __restrict__ w3T,
                                  int G, int Gpad)
{
  __shared__ float t[32][33];
  int z = blockIdx.z;
  const float* in = (z==0)? lw : (z==1)? w1 : (z==2)? w2 : w3;
  u16* out        = (z==0)? lwT: (z==1)? w1T: (z==2)? w2T: w3T;
  int R   = (z==0)? G : 256;
  int ldo = (z==0)? Gpad : 256;
  int by = blockIdx.y, bx = blockIdx.x;
  if (by*32 >= R && z != 0) return;       // z==0 must still zero-fill pad rows
  int tid = threadIdx.x;
  #pragma unroll
  for (int k=0;k<4;k++){
    int p = tid + k*256; int r = p>>5, c = p&31;
    int gr = by*32 + r;
    t[r][c] = (gr < R) ? in[gr*256 + bx*32 + c] : 0.f;
  }
  __syncthreads();
  #pragma unroll
  for (int k=0;k<4;k++){
    int p = tid + k*256; int r = p>>5, c = p&31;
    int oc = by*32 + c;
    if (oc < ldo) out[(bx*32 + r)*ldo + oc] = f2h(t[c][r]);
  }
}

// ---- CSR build ----
__global__ void count_kernel(const int* __restrict__ dst, int* __restrict__ cnt, int E){
  int e = blockIdx.x*256 + threadIdx.x;
  if (e < E) atomicAdd(&cnt[dst[e]], 1);
}

__global__ void scan_reduce(const int* __restrict__ cnt, int* __restrict__ bsum, int N){
  __shared__ int s[256];
  int tid = threadIdx.x;
  int i = blockIdx.x*256 + tid;
  s[tid] = (i<N)? cnt[i] : 0;
  __syncthreads();
  for (int off=128; off>0; off>>=1){
    if (tid < off) s[tid] += s[tid+off];
    __syncthreads();
  }
  if (tid==0) bsum[blockIdx.x] = s[0];
}

__global__ void scan_offsets(const int* __restrict__ bsum, int* __restrict__ boff, int nb){
  __shared__ int s[256];
  int tid = threadIdx.x;
  int v = (tid<nb)? bsum[tid] : 0;
  s[tid] = v; __syncthreads();
  for (int off=1; off<256; off<<=1){
    int t = (tid>=off)? s[tid-off] : 0;
    __syncthreads();
    s[tid] += t;
    __syncthreads();
  }
  if (tid<nb) boff[tid] = s[tid]-v;
}

__global__ void scan_final(const int* __restrict__ cnt, const int* __restrict__ boff,
                           int* __restrict__ row_ptr, float* __restrict__ dinv, int N, int E){
  __shared__ int s[256];
  int tid = threadIdx.x;
  int i = blockIdx.x*256 + tid;
  int v = (i<N)? cnt[i] : 0;
  s[tid] = v; __syncthreads();
  for (int off=1; off<256; off<<=1){
    int t = (tid>=off)? s[tid-off] : 0;
    __syncthreads();
    s[tid] += t;
    __syncthreads();
  }
  if (i < N){
    row_ptr[i] = boff[blockIdx.x] + s[tid] - v;
    dinv[i] = rsqrtf((float)(v+1));
  }
  if (i == N-1) row_ptr[N] = E;
}

__global__ void scatter_kernel(const int* __restrict__ src, const int* __restrict__ dst,
                               const int* __restrict__ row_ptr, int* __restrict__ cursor,
                               int* __restrict__ colx, int E){
  int e = blockIdx.x*256 + threadIdx.x;
  if (e < E){
    int d = dst[e];
    int pos = atomicAdd(&cursor[d], 1);
    colx[row_ptr[d] + pos] = src[e];
  }
}

// ---- GEMM: C[M x 256] = A @ BT^T, fp16 MFMA, m97-style async staging ----
// XPATH: A fp32 [M x lda], Ka valid cols (< Kpad); else A fp16 [M x lda], lda==Kpad.
// BT fp16 [256 x Kpad], fully zero-padded.
template<bool XPATH, bool ADD_BIAS>
__global__ __launch_bounds__(256) void gemm_async(
    const void* __restrict__ Av, int lda, int Ka,
    const u16* __restrict__ BT, int Kpad,
    u16* __restrict__ C, const float* __restrict__ bias, int M)
{
  // A tile: 128x32. XPATH: fp32 (16KB), else fp16 (8KB). B tile: 128x32 fp16 (8KB).
  __shared__ __align__(16) char AsRaw[XPATH ? 16384 : 8192];
  __shared__ __align__(16) u16  Bs[128*32];
  float* Asf = (float*)AsRaw;
  u16*   Ash = (u16*)AsRaw;

  const int tid  = threadIdx.x;
  const int lane = tid & 63;
  const int quad = lane >> 4;
  const int l16  = lane & 15;
  const int wave = tid >> 6;
  const int wm = (wave >> 1) << 6;
  const int wn = (wave & 1) << 6;
  const int m0 = blockIdx.y << 7;
  const int n0 = blockIdx.x << 7;

  // B staging: chunk q = wave*2+i covers rows q*16..+15; lane: row q*16+(l>>2), col (l&3)*8 fp16
  const u16* bg[2];
  u16* lB[2];
  #pragma unroll
  for (int i=0;i<2;i++){
    int q = wave*2 + i;
    bg[i] = BT + (size_t)(n0 + q*16 + (lane>>2))*Kpad + (lane&3)*8;
    lB[i] = Bs + q*512;
  }

  // A staging addresses
  const float* agf[4]; u16* lAf[4];
  const u16*   agh[2]; u16* lAh[2];
  if constexpr (XPATH){
    const float* Af = (const float*)Av;
    #pragma unroll
    for (int i=0;i<4;i++){
      int q = wave*4 + i;                  // 16 chunks of 8 rows
      int gr = m0 + q*8 + (lane>>3);
      if (gr >= M) gr = M-1;
      agf[i] = Af + (size_t)gr*lda + (lane&7)*4;
      lAf[i] = (u16*)(Asf + q*256);
    }
  } else {
    const u16* Ah = (const u16*)Av;
    #pragma unroll
    for (int i=0;i<2;i++){
      int q = wave*2 + i;                  // 8 chunks of 16 rows
      int gr = m0 + q*16 + (lane>>2);
      if (gr >= M) gr = M-1;
      agh[i] = Ah + (size_t)gr*lda + (lane&3)*8;
      lAh[i] = Ash + q*512;
    }
  }

  f32x4 acc[4][4];
  #pragma unroll
  for (int i=0;i<4;i++)
    #pragma unroll
    for (int j=0;j<4;j++) acc[i][j] = {0.f,0.f,0.f,0.f};

  for (int k0 = 0; k0 < Kpad; k0 += 32){
    bool tail = XPATH && (k0 + 32 > Ka);
    // B always async
    #pragma unroll
    for (int i=0;i<2;i++) async16(lB[i], bg[i] + k0);
    if constexpr (XPATH){
      if (!tail){
        #pragma unroll
        for (int i=0;i<4;i++) async16(lAf[i], agf[i] + k0);
      } else {
        // manual zero-padded staging of the K-tail (uniform branch, 1 of 32 iters)
        const float* Af = (const float*)Av;
        int row = tid >> 1, cb = (tid & 1)*16;
        int gr = m0 + row;
        bool rv = gr < M;
        float* dst = Asf + row*32 + cb;
        #pragma unroll
        for (int c=0;c<16;c++){
          int gc = k0 + cb + c;
          dst[c] = (rv && gc < Ka) ? Af[(size_t)gr*lda + gc] : 0.f;
        }
      }
    } else {
      #pragma unroll
      for (int i=0;i<2;i++) async16(lAh[i], agh[i] + k0);
    }
    asm volatile("s_waitcnt vmcnt(0)" ::: "memory");
    __syncthreads();

    f16x8 af[4], bf[4];
    if constexpr (XPATH){
      #pragma unroll
      for (int mt=0;mt<4;mt++){
        const float* ap = Asf + (wm + mt*16 + l16)*32 + quad*8;
        f32x4 lo = *(const f32x4*)ap;
        f32x4 hi = *(const f32x4*)(ap + 4);
        union { f16x8 v; u32 w[4]; } u;
        u.w[0] = __builtin_bit_cast(u32, __builtin_amdgcn_cvt_pkrtz(lo[0], lo[1]));
        u.w[1] = __builtin_bit_cast(u32, __builtin_amdgcn_cvt_pkrtz(lo[2], lo[3]));
        u.w[2] = __builtin_bit_cast(u32, __builtin_amdgcn_cvt_pkrtz(hi[0], hi[1]));
        u.w[3] = __builtin_bit_cast(u32, __builtin_amdgcn_cvt_pkrtz(hi[2], hi[3]));
        af[mt] = u.v;
      }
    } else {
      #pragma unroll
      for (int mt=0;mt<4;mt++)
        af[mt] = __builtin_bit_cast(f16x8, *(const u16x8*)(Ash + (wm + mt*16 + l16)*32 + quad*8));
    }
    #pragma unroll
    for (int nt=0;nt<4;nt++)
      bf[nt] = __builtin_bit_cast(f16x8, *(const u16x8*)(Bs + (wn + nt*16 + l16)*32 + quad*8));
    #pragma unroll
    for (int mt=0;mt<4;mt++)
      #pragma unroll
      for (int nt=0;nt<4;nt++)
        acc[mt][nt] = __builtin_amdgcn_mfma_f32_16x16x32_f16(af[mt], bf[nt], acc[mt][nt], 0, 0, 0);
    __syncthreads();
  }

  #pragma unroll
  for (int mt=0;mt<4;mt++){
    #pragma unroll
    for (int nt=0;nt<4;nt++){
      int col = n0 + wn + nt*16 + l16;
      float bv = 0.f;
      if constexpr (ADD_BIAS) bv = bias[col];
      #pragma unroll
      for (int r=0;r<4;r++){
        int row = m0 + wm + mt*16 + quad*4 + r;
        if (row < M) C[(size_t)row*256 + col] = f2h(acc[mt][nt][r] + bv);
      }
    }
  }
}

// ---- GCN aggregation: H[i] = relu( sum_e dinv[s]*dinv[i]*XW[s] + dinv[i]^2*XW[i] + b ) ----
__global__ __launch_bounds__(256) void agg_kernel(
    const u16* __restrict__ XW, const float* __restrict__ bias,
    const float* __restrict__ dinv, const int* __restrict__ row_ptr,
    const int* __restrict__ colx, u16* __restrict__ H, int N)
{
  int wid = (blockIdx.x << 2) + (threadIdx.x >> 6);
  if (wid >= N) return;
  int lane = threadIdx.x & 63;
  int f = lane << 2;
  float di = dinv[wid];
  int e0 = row_ptr[wid], e1 = row_ptr[wid+1];
  int deg = e1 - e0;
  float a0=0.f, a1=0.f, a2=0.f, a3=0.f;
  for (int base = 0; base < deg; base += 64){
    int mi = 0;
    if (base + lane < deg) mi = colx[e0 + base + lane];
    int cnt = min(deg - base, 64);
    int j = 0;
    for (; j+1 < cnt; j += 2){
      int s0 = __shfl(mi, j);
      int s1 = __shfl(mi, j+1);
      float w0 = dinv[s0]*di;
      float w1 = dinv[s1]*di;
      u16x4 x0 = *(const u16x4*)(XW + (size_t)s0*256 + f);
      u16x4 x1 = *(const u16x4*)(XW + (size_t)s1*256 + f);
      a0 += w0*h2f(x0[0]) + w1*h2f(x1[0]);
      a1 += w0*h2f(x0[1]) + w1*h2f(x1[1]);
      a2 += w0*h2f(x0[2]) + w1*h2f(x1[2]);
      a3 += w0*h2f(x0[3]) + w1*h2f(x1[3]);
    }
    if (j < cnt){
      int s0 = __shfl(mi, j);
      float w0 = dinv[s0]*di;
      u16x4 x0 = *(const u16x4*)(XW + (size_t)s0*256 + f);
      a0 += w0*h2f(x0[0]); a1 += w0*h2f(x0[1]);
      a2 += w0*h2f(x0[2]); a3 += w0*h2f(x0[3]);
    }
  }
  u16x4 xs = *(const u16x4*)(XW + (size_t)wid*256 + f);
  float wd = di*di;
  a0 += wd*h2f(xs[0]); a1 += wd*h2f(xs[1]); a2 += wd*h2f(xs[2]); a3 += wd*h2f(xs[3]);
  const float4 bb = *(const float4*)(bias + f);
  a0 = fmaxf(a0 + bb.x, 0.f);
  a1 = fmaxf(a1 + bb.y, 0.f);
  a2 = fmaxf(a2 + bb.z, 0.f);
  a3 = fmaxf(a3 + bb.w, 0.f);
  u16x4 o = { f2h(a0), f2h(a1), f2h(a2), f2h(a3) };
  *(u16x4*)(H + (size_t)wid*256 + f) = o;
}

// ---- BN stats over axis 0 ----
__global__ void bn_stats(const u16* __restrict__ H, float* __restrict__ bsum,
                         float* __restrict__ bsq, int N){
  int col = threadIdx.x;
  float s=0.f, q=0.f;
  for (int r=blockIdx.x; r<N; r+=gridDim.x){
    float v = h2f(H[(size_t)r*256 + col]);
    s += v; q += v*v;
  }
  atomicAdd(&bsum[col], s);
  atomicAdd(&bsq[col], q);
}

__global__ void bn_finalize(const float* __restrict__ bsum, const float* __restrict__ bsq,
                            const float* __restrict__ gamma, const float* __restrict__ beta,
                            float* __restrict__ scale, float* __restrict__ shift, int N){
  int c = threadIdx.x;
  float invN = 1.f/(float)N;
  float mu  = bsum[c]*invN;
  float var = bsq[c]*invN - mu*mu;
  float sc  = gamma[c] * rsqrtf(var + 1e-5f);
  scale[c] = sc;
  shift[c] = beta[c] - mu*sc;
}

// ---- BN-apply + relu + mlp2 + softmax ----
__global__ __launch_bounds__(256) void final_kernel(
    const u16* __restrict__ H, const float* __restrict__ scale, const float* __restrict__ shift,
    const float* __restrict__ W2, const float* __restrict__ b2, float* __restrict__ out, int N)
{
  __shared__ float W2s[256*20];
  __shared__ float scs[256];
  __shared__ float shs[256];
  __shared__ float b2s[20];
  int tid = threadIdx.x;
  for (int i=tid; i<5120; i+=256) W2s[i] = W2[i];
  scs[tid] = scale[tid];
  shs[tid] = shift[tid];
  if (tid < 20) b2s[tid] = b2[tid];
  __syncthreads();
  int r = blockIdx.x*256 + tid;
  if (r >= N) return;
  float l[20];
  #pragma unroll
  for (int c=0;c<20;c++) l[c] = b2s[c];
  const u16* hrow = H + (size_t)r*256;
  for (int j0=0;j0<256;j0+=8){
    u16x8 h8 = *(const u16x8*)(hrow + j0);
    #pragma unroll
    for (int t=0;t<8;t++){
      int j = j0+t;
      float a = fmaxf(fmaf(h2f(h8[t]), scs[j], shs[j]), 0.f);
      const float* wr = W2s + j*20;
      #pragma unroll
      for (int c=0;c<20;c++) l[c] = fmaf(a, wr[c], l[c]);
    }
  }
  float m = l[0];
  #pragma unroll
  for (int c=1;c<20;c++) m = fmaxf(m, l[c]);
  float ssum = 0.f;
  #pragma unroll
  for (int c=0;c<20;c++){ l[c] = __expf(l[c]-m); ssum += l[c]; }
  float inv = 1.f/ssum;
  float* orow = out + (size_t)r*20;
  #pragma unroll
  for (int c=0;c<20;c++) orow[c] = l[c]*inv;
}

extern "C" void kernel_launch(void* const* d_in, const int* in_sizes, int n_in,
                              void* d_out, int out_size, void* d_ws, size_t ws_size,
                              hipStream_t stream)
{
  (void)n_in; (void)out_size; (void)ws_size;
  const float* x     = (const float*)d_in[0];
  const int*   ei    = (const int*)d_in[1];
  const float* lin_w = (const float*)d_in[2];
  const float* c1w   = (const float*)d_in[3];
  const float* c1b   = (const float*)d_in[4];
  const float* c2w   = (const float*)d_in[5];
  const float* c2b   = (const float*)d_in[6];
  const float* m1w   = (const float*)d_in[7];
  const float* m1b   = (const float*)d_in[8];
  const float* gam   = (const float*)d_in[9];
  const float* bet   = (const float*)d_in[10];
  const float* m2w   = (const float*)d_in[11];
  const float* m2b   = (const float*)d_in[12];
  float* out = (float*)d_out;

  const int E = in_sizes[1]/2;
  const int G = in_sizes[2]/256;          // 1002
  const int N = in_sizes[0]/G;            // 50000
  const int Gpad = (G + 31) & ~31;        // 1024
  const int* srcI = ei;
  const int* dstI = ei + E;

  char* w = (char*)d_ws;
  auto alloc = [&](size_t bytes)->char*{
    char* p = w;
    w += (bytes + 255) & ~(size_t)255;
    return p;
  };
  u16* Ha    = (u16*)alloc((size_t)N*256*2);
  u16* Hb    = (u16*)alloc((size_t)N*256*2);
  u16* linT  = (u16*)alloc((size_t)256*Gpad*2);
  u16* w1T   = (u16*)alloc(256*256*2);
  u16* w2T   = (u16*)alloc(256*256*2);
  u16* w3T   = (u16*)alloc(256*256*2);
  int* cnt    = (int*)alloc((size_t)N*4);
  int* cursor = (int*)alloc((size_t)N*4);
  int* rowp   = (int*)alloc((size_t)(N+1)*4);
  int* colx   = (int*)alloc((size_t)E*4);
  float* dinv = (float*)alloc((size_t)N*4);
  int* bsum   = (int*)alloc(1024);
  int* boff   = (int*)alloc(1024);
  float* bnsum= (float*)alloc(1024);
  float* bnsq = (float*)alloc(1024);
  float* scl  = (float*)alloc(1024);
  float* shf  = (float*)alloc(1024);

  hipMemsetAsync(cnt,    0, (size_t)N*4, stream);
  hipMemsetAsync(cursor, 0, (size_t)N*4, stream);
  hipMemsetAsync(bnsum,  0, 2048, stream);               // bnsum + bnsq (contiguous)

  const int NB = (N + 255)/256;

  transpose_weights<<<dim3(8, Gpad>>5, 4), 256, 0, stream>>>(
      lin_w, c1w, c2w, m1w, linT, w1T, w2T, w3T, G, Gpad);
  count_kernel  <<<dim3((E+255)/256), 256, 0, stream>>>(dstI, cnt, E);
  scan_reduce   <<<dim3(NB), 256, 0, stream>>>(cnt, bsum, N);
  scan_offsets  <<<dim3(1),  256, 0, stream>>>(bsum, boff, NB);
  scan_final    <<<dim3(NB), 256, 0, stream>>>(cnt, boff, rowp, dinv, N, E);
  scatter_kernel<<<dim3((E+255)/256), 256, 0, stream>>>(srcI, dstI, rowp, cursor, colx, E);

  dim3 ggrid(2, (N+127)/128);
  gemm_async<true,  false><<<ggrid, 256, 0, stream>>>(x,  G,   G,   linT, Gpad, Ha, nullptr, N);
  gemm_async<false, false><<<ggrid, 256, 0, stream>>>(Ha, 256, 256, w1T,  256,  Hb, nullptr, N);
  agg_kernel<<<dim3((N+3)/4), 256, 0, stream>>>(Hb, c1b, dinv, rowp, colx, Ha, N);
  gemm_async<false, false><<<ggrid, 256, 0, stream>>>(Ha, 256, 256, w2T,  256,  Hb, nullptr, N);
  agg_kernel<<<dim3((N+3)/4), 256, 0, stream>>>(Hb, c2b, dinv, rowp, colx, Ha, N);
  gemm_async<false, true ><<<ggrid, 256, 0, stream>>>(Ha, 256, 256, w3T,  256,  Hb, m1b, N);
  bn_stats   <<<dim3(256), 256, 0, stream>>>(Hb, bnsum, bnsq, N);
  bn_finalize<<<dim3(1),   256, 0, stream>>>(bnsum, bnsq, gam, bet, scl, shf, N);
  final_kernel<<<dim3(NB), 256, 0, stream>>>(Hb, scl, shf, m2w, m2b, out, N);
}

// Round 4
// 729.920 us; speedup vs baseline: 1.3371x; 1.0019x over previous
//
#include <hip/hip_runtime.h>
#include <cstdint>
#include <cstddef>

typedef unsigned short u16;
typedef unsigned int   u32;
typedef _Float16       f16;
typedef u16  u16x4 __attribute__((ext_vector_type(4)));
typedef u16  u16x8 __attribute__((ext_vector_type(8)));
typedef f16  f16x8 __attribute__((ext_vector_type(8)));
typedef float f32x4 __attribute__((ext_vector_type(4)));

static __device__ __forceinline__ u16 f2h(float f){
  f16 h = (f16)f;
  return __builtin_bit_cast(u16, h);
}
static __device__ __forceinline__ float h2f(u16 b){
  f16 h = __builtin_bit_cast(f16, b);
  return (float)h;
}

// async global->LDS, 16B per lane. lds base must be wave-uniform; HW adds lane*16.
static __device__ __forceinline__ void async16(void* lds, const void* g){
  __builtin_amdgcn_global_load_lds(
      (const __attribute__((address_space(1))) u32*)g,
      (__attribute__((address_space(3))) u32*)lds, 16, 0, 0);
}

// ---- transpose 4 weight matrices (fp32 in) -> fp16 out, K-contiguous ----
__global__ void transpose_weights(const float* __restrict__ lw, const float* __restrict__ w1,
                                  const float* __restrict__ w2, const float* __restrict__ w3,
                                  u16* __restrict__ lwT, u16* __restrict__ w1T,
                                  u16* __restrict__ w2T, u16* __restrict__ w3T,
                                  int G, int Gpad)
{
  __shared__ float t[32][33];
  int z = blockIdx.z;
  const float* in = (z==0)? lw : (z==1)? w1 : (z==2)? w2 : w3;
  u16* out        = (z==0)? lwT: (z==1)? w1T: (z==2)? w2T: w3T;
  int R   = (z==0)? G : 256;
  int ldo = (z==0)? Gpad : 256;
  int by = blockIdx.y, bx = blockIdx.x;
  if (by*32 >= R && z != 0) return;       // z==0 must still zero-fill pad rows
  int tid = threadIdx.x;
  #pragma unroll
  for (int k=0;k<4;k++){
    int p = tid + k*256; int r = p>>5, c = p&31;
    int gr = by*32 + r;
    t[r][c] = (gr < R) ? in[gr*256 + bx*32 + c] : 0.f;
  }
  __syncthreads();
  #pragma unroll
  for (int k=0;k<4;k++){
    int p = tid + k*256; int r = p>>5, c = p&31;
    int oc = by*32 + c;
    if (oc < ldo) out[(bx*32 + r)*ldo + oc] = f2h(t[c][r]);
  }
}

// ---- CSR build ----
__global__ void count_kernel(const int* __restrict__ dst, int* __restrict__ cnt, int E){
  int e = blockIdx.x*256 + threadIdx.x;
  if (e < E) atomicAdd(&cnt[dst[e]], 1);
}

__global__ void scan_reduce(const int* __restrict__ cnt, int* __restrict__ bsum, int N){
  __shared__ int s[256];
  int tid = threadIdx.x;
  int i = blockIdx.x*256 + tid;
  s[tid] = (i<N)? cnt[i] : 0;
  __syncthreads();
  for (int off=128; off>0; off>>=1){
    if (tid < off) s[tid] += s[tid+off];
    __syncthreads();
  }
  if (tid==0) bsum[blockIdx.x] = s[0];
}

__global__ void scan_offsets(const int* __restrict__ bsum, int* __restrict__ boff, int nb){
  __shared__ int s[256];
  int tid = threadIdx.x;
  int v = (tid<nb)? bsum[tid] : 0;
  s[tid] = v; __syncthreads();
  for (int off=1; off<256; off<<=1){
    int t = (tid>=off)? s[tid-off] : 0;
    __syncthreads();
    s[tid] += t;
    __syncthreads();
  }
  if (tid<nb) boff[tid] = s[tid]-v;
}

__global__ void scan_final(const int* __restrict__ cnt, const int* __restrict__ boff,
                           int* __restrict__ row_ptr, float* __restrict__ dinv, int N, int E){
  __shared__ int s[256];
  int tid = threadIdx.x;
  int i = blockIdx.x*256 + tid;
  int v = (i<N)? cnt[i] : 0;
  s[tid] = v; __syncthreads();
  for (int off=1; off<256; off<<=1){
    int t = (tid>=off)? s[tid-off] : 0;
    __syncthreads();
    s[tid] += t;
    __syncthreads();
  }
  if (i < N){
    row_ptr[i] = boff[blockIdx.x] + s[tid] - v;
    dinv[i] = rsqrtf((float)(v+1));
  }
  if (i == N-1) row_ptr[N] = E;
}

__global__ void scatter_kernel(const int* __restrict__ src, const int* __restrict__ dst,
                               const int* __restrict__ row_ptr, int* __restrict__ cursor,
                               int* __restrict__ colx, int E){
  int e = blockIdx.x*256 + threadIdx.x;
  if (e < E){
    int d = dst[e];
    int pos = atomicAdd(&cursor[d], 1);
    colx[row_ptr[d] + pos] = src[e];
  }
}

// ---- GEMM: C[M x 256] = A @ BT^T, fp16 MFMA, async staging + XOR-swizzled LDS ----
// XPATH: A fp32 [M x lda], Ka valid cols (< Kpad); else A fp16 [M x lda], lda==Kpad.
// BT fp16 [256 x Kpad], fully zero-padded.
// Swizzle (kills ds_read bank conflicts; staging dest is fixed lane*16 so the
// permutation is applied to the GLOBAL source column):
//   fp32 rows (8x16B granules): slot s holds data group s ^ (row&7)
//   fp16 rows (4x16B granules): slot s holds data group s ^ ((row>>1)&3)
template<bool XPATH, bool ADD_BIAS>
__global__ __launch_bounds__(256) void gemm_async(
    const void* __restrict__ Av, int lda, int Ka,
    const u16* __restrict__ BT, int Kpad,
    u16* __restrict__ C, const float* __restrict__ bias, int M)
{
  __shared__ __align__(16) char AsRaw[XPATH ? 16384 : 8192];
  __shared__ __align__(16) u16  Bs[128*32];
  float* Asf = (float*)AsRaw;
  u16*   Ash = (u16*)AsRaw;

  const int tid  = threadIdx.x;
  const int lane = tid & 63;
  const int quad = lane >> 4;
  const int l16  = lane & 15;
  const int wave = tid >> 6;
  const int wm = (wave >> 1) << 6;
  const int wn = (wave & 1) << 6;
  const int m0 = blockIdx.y << 7;
  const int n0 = blockIdx.x << 7;

  // B staging: chunk q = wave*2+i covers rows q*16..+15.
  // lane -> (rr = lane>>2, ss = lane&3); source group = ss ^ ((rr>>1)&3)
  const u16* bg[2];
  u16* lB[2];
  #pragma unroll
  for (int i=0;i<2;i++){
    int q = wave*2 + i;
    int rr = lane >> 2, ss = lane & 3;
    int gg = ss ^ ((rr >> 1) & 3);
    bg[i] = BT + (size_t)(n0 + q*16 + rr)*Kpad + gg*8;
    lB[i] = Bs + q*512;
  }

  // A staging addresses
  const float* agf[4]; u16* lAf[4];
  const u16*   agh[2]; u16* lAh[2];
  if constexpr (XPATH){
    const float* Af = (const float*)Av;
    #pragma unroll
    for (int i=0;i<4;i++){
      int q = wave*4 + i;                  // 16 chunks of 8 rows
      int rr = lane >> 3, ss = lane & 7;
      int gg = ss ^ rr;                    // rr in [0,8): row&7 == rr
      int gr = m0 + q*8 + rr;
      if (gr >= M) gr = M-1;
      agf[i] = Af + (size_t)gr*lda + gg*4;
      lAf[i] = (u16*)(Asf + q*256);
    }
  } else {
    const u16* Ah = (const u16*)Av;
    #pragma unroll
    for (int i=0;i<2;i++){
      int q = wave*2 + i;                  // 8 chunks of 16 rows
      int rr = lane >> 2, ss = lane & 3;
      int gg = ss ^ ((rr >> 1) & 3);
      int gr = m0 + q*16 + rr;
      if (gr >= M) gr = M-1;
      agh[i] = Ah + (size_t)gr*lda + gg*8;
      lAh[i] = Ash + q*512;
    }
  }

  f32x4 acc[4][4];
  #pragma unroll
  for (int i=0;i<4;i++)
    #pragma unroll
    for (int j=0;j<4;j++) acc[i][j] = {0.f,0.f,0.f,0.f};

  for (int k0 = 0; k0 < Kpad; k0 += 32){
    bool tail = XPATH && (k0 + 32 > Ka);
    #pragma unroll
    for (int i=0;i<2;i++) async16(lB[i], bg[i] + k0);
    if constexpr (XPATH){
      if (!tail){
        #pragma unroll
        for (int i=0;i<4;i++) async16(lAf[i], agf[i] + k0);
      } else {
        // manual zero-padded staging of the K-tail, same swizzle
        const float* Af = (const float*)Av;
        int row = tid >> 1, half = tid & 1;
        int gr = m0 + row;
        bool rv = gr < M;
        #pragma unroll
        for (int g2=0; g2<4; g2++){
          int g = half*4 + g2;
          int slot = g ^ (row & 7);
          float* dst = Asf + row*32 + slot*4;
          #pragma unroll
          for (int c=0;c<4;c++){
            int gc = k0 + g*4 + c;
            dst[c] = (rv && gc < Ka) ? Af[(size_t)gr*lda + gc] : 0.f;
          }
        }
      }
    } else {
      #pragma unroll
      for (int i=0;i<2;i++) async16(lAh[i], agh[i] + k0);
    }
    asm volatile("s_waitcnt vmcnt(0)" ::: "memory");
    __syncthreads();

    f16x8 af[4], bf[4];
    if constexpr (XPATH){
      #pragma unroll
      for (int mt=0;mt<4;mt++){
        int R = wm + mt*16 + l16;
        const float* rb = Asf + R*32;
        int x7 = R & 7;
        int s0 = (quad*2)   ^ x7;
        int s1 = (quad*2+1) ^ x7;
        f32x4 lo = *(const f32x4*)(rb + s0*4);
        f32x4 hi = *(const f32x4*)(rb + s1*4);
        union { f16x8 v; u32 w[4]; } u;
        u.w[0] = __builtin_bit_cast(u32, __builtin_amdgcn_cvt_pkrtz(lo[0], lo[1]));
        u.w[1] = __builtin_bit_cast(u32, __builtin_amdgcn_cvt_pkrtz(lo[2], lo[3]));
        u.w[2] = __builtin_bit_cast(u32, __builtin_amdgcn_cvt_pkrtz(hi[0], hi[1]));
        u.w[3] = __builtin_bit_cast(u32, __builtin_amdgcn_cvt_pkrtz(hi[2], hi[3]));
        af[mt] = u.v;
      }
    } else {
      #pragma unroll
      for (int mt=0;mt<4;mt++){
        int R = wm + mt*16 + l16;
        int s = quad ^ ((R >> 1) & 3);
        af[mt] = __builtin_bit_cast(f16x8, *(const u16x8*)(Ash + R*32 + s*8));
      }
    }
    #pragma unroll
    for (int nt=0;nt<4;nt++){
      int R = wn + nt*16 + l16;
      int s = quad ^ ((R >> 1) & 3);
      bf[nt] = __builtin_bit_cast(f16x8, *(const u16x8*)(Bs + R*32 + s*8));
    }
    #pragma unroll
    for (int mt=0;mt<4;mt++)
      #pragma unroll
      for (int nt=0;nt<4;nt++)
        acc[mt][nt] = __builtin_amdgcn_mfma_f32_16x16x32_f16(af[mt], bf[nt], acc[mt][nt], 0, 0, 0);
    __syncthreads();
  }

  #pragma unroll
  for (int mt=0;mt<4;mt++){
    #pragma unroll
    for (int nt=0;nt<4;nt++){
      int col = n0 + wn + nt*16 + l16;
      float bv = 0.f;
      if constexpr (ADD_BIAS) bv = bias[col];
      #pragma unroll
      for (int r=0;r<4;r++){
        int row = m0 + wm + mt*16 + quad*4 + r;
        if (row < M) C[(size_t)row*256 + col] = f2h(acc[mt][nt][r] + bv);
      }
    }
  }
}

// ---- GCN aggregation: H[i] = relu( sum_e dinv[s]*dinv[i]*XW[s] + dinv[i]^2*XW[i] + b ) ----
__global__ __launch_bounds__(256) void agg_kernel(
    const u16* __restrict__ XW, const float* __restrict__ bias,
    const float* __restrict__ dinv, const int* __restrict__ row_ptr,
    const int* __restrict__ colx, u16* __restrict__ H, int N)
{
  int wid = (blockIdx.x << 2) + (threadIdx.x >> 6);
  if (wid >= N) return;
  int lane = threadIdx.x & 63;
  int f = lane << 2;
  float di = dinv[wid];
  int e0 = row_ptr[wid], e1 = row_ptr[wid+1];
  int deg = e1 - e0;
  float a0=0.f, a1=0.f, a2=0.f, a3=0.f;
  for (int base = 0; base < deg; base += 64){
    int mi = 0;
    if (base + lane < deg) mi = colx[e0 + base + lane];
    int cnt = min(deg - base, 64);
    int j = 0;
    for (; j+1 < cnt; j += 2){
      int s0 = __shfl(mi, j);
      int s1 = __shfl(mi, j+1);
      float w0 = dinv[s0]*di;
      float w1 = dinv[s1]*di;
      u16x4 x0 = *(const u16x4*)(XW + (size_t)s0*256 + f);
      u16x4 x1 = *(const u16x4*)(XW + (size_t)s1*256 + f);
      a0 += w0*h2f(x0[0]) + w1*h2f(x1[0]);
      a1 += w0*h2f(x0[1]) + w1*h2f(x1[1]);
      a2 += w0*h2f(x0[2]) + w1*h2f(x1[2]);
      a3 += w0*h2f(x0[3]) + w1*h2f(x1[3]);
    }
    if (j < cnt){
      int s0 = __shfl(mi, j);
      float w0 = dinv[s0]*di;
      u16x4 x0 = *(const u16x4*)(XW + (size_t)s0*256 + f);
      a0 += w0*h2f(x0[0]); a1 += w0*h2f(x0[1]);
      a2 += w0*h2f(x0[2]); a3 += w0*h2f(x0[3]);
    }
  }
  u16x4 xs = *(const u16x4*)(XW + (size_t)wid*256 + f);
  float wd = di*di;
  a0 += wd*h2f(xs[0]); a1 += wd*h2f(xs[1]); a2 += wd*h2f(xs[2]); a3 += wd*h2f(xs[3]);
  const float4 bb = *(const float4*)(bias + f);
  a0 = fmaxf(a0 + bb.x, 0.f);
  a1 = fmaxf(a1 + bb.y, 0.f);
  a2 = fmaxf(a2 + bb.z, 0.f);
  a3 = fmaxf(a3 + bb.w, 0.f);
  u16x4 o = { f2h(a0), f2h(a1), f2h(a2), f2h(a3) };
  *(u16x4*)(H + (size_t)wid*256 + f) = o;
}

// ---- BN stats over axis 0 ----
__global__ void bn_stats(const u16* __restrict__ H, float* __restrict__ bsum,
                         float* __restrict__ bsq, int N){
  int col = threadIdx.x;
  float s=0.f, q=0.f;
  for (int r=blockIdx.x; r<N; r+=gridDim.x){
    float v = h2f(H[(size_t)r*256 + col]);
    s += v; q += v*v;
  }
  atomicAdd(&bsum[col], s);
  atomicAdd(&bsq[col], q);
}

__global__ void bn_finalize(const float* __restrict__ bsum, const float* __restrict__ bsq,
                            const float* __restrict__ gamma, const float* __restrict__ beta,
                            float* __restrict__ scale, float* __restrict__ shift, int N){
  int c = threadIdx.x;
  float invN = 1.f/(float)N;
  float mu  = bsum[c]*invN;
  float var = bsq[c]*invN - mu*mu;
  float sc  = gamma[c] * rsqrtf(var + 1e-5f);
  scale[c] = sc;
  shift[c] = beta[c] - mu*sc;
}

// ---- BN-apply + relu + mlp2 + softmax ----
__global__ __launch_bounds__(256) void final_kernel(
    const u16* __restrict__ H, const float* __restrict__ scale, const float* __restrict__ shift,
    const float* __restrict__ W2, const float* __restrict__ b2, float* __restrict__ out, int N)
{
  __shared__ float W2s[256*20];
  __shared__ float scs[256];
  __shared__ float shs[256];
  __shared__ float b2s[20];
  int tid = threadIdx.x;
  for (int i=tid; i<5120; i+=256) W2s[i] = W2[i];
  scs[tid] = scale[tid];
  shs[tid] = shift[tid];
  if (tid < 20) b2s[tid] = b2[tid];
  __syncthreads();
  int r = blockIdx.x*256 + tid;
  if (r >= N) return;
  float l[20];
  #pragma unroll
  for (int c=0;c<20;c++) l[c] = b2s[c];
  const u16* hrow = H + (size_t)r*256;
  for (int j0=0;j0<256;j0+=8){
    u16x8 h8 = *(const u16x8*)(hrow + j0);
    #pragma unroll
    for (int t=0;t<8;t++){
      int j = j0+t;
      float a = fmaxf(fmaf(h2f(h8[t]), scs[j], shs[j]), 0.f);
      const float* wr = W2s + j*20;
      #pragma unroll
      for (int c=0;c<20;c++) l[c] = fmaf(a, wr[c], l[c]);
    }
  }
  float m = l[0];
  #pragma unroll
  for (int c=1;c<20;c++) m = fmaxf(m, l[c]);
  float ssum = 0.f;
  #pragma unroll
  for (int c=0;c<20;c++){ l[c] = __expf(l[c]-m); ssum += l[c]; }
  float inv = 1.f/ssum;
  float* orow = out + (size_t)r*20;
  #pragma unroll
  for (int c=0;c<20;c++) orow[c] = l[c]*inv;
}

extern "C" void kernel_launch(void* const* d_in, const int* in_sizes, int n_in,
                              void* d_out, int out_size, void* d_ws, size_t ws_size,
                              hipStream_t stream)
{
  (void)n_in; (void)out_size; (void)ws_size;
  const float* x     = (const float*)d_in[0];
  const int*   ei    = (const int*)d_in[1];
  const float* lin_w = (const float*)d_in[2];
  const float* c1w   = (const float*)d_in[3];
  const float* c1b   = (const float*)d_in[4];
  const float* c2w   = (const float*)d_in[5];
  const float* c2b   = (const float*)d_in[6];
  const float* m1w   = (const float*)d_in[7];
  const float* m1b   = (const float*)d_in[8];
  const float* gam   = (const float*)d_in[9];
  const float* bet   = (const float*)d_in[10];
  const float* m2w   = (const float*)d_in[11];
  const float* m2b   = (const float*)d_in[12];
  float* out = (float*)d_out;

  const int E = in_sizes[1]/2;
  const int G = in_sizes[2]/256;          // 1002
  const int N = in_sizes[0]/G;            // 50000
  const int Gpad = (G + 31) & ~31;        // 1024
  const int* srcI = ei;
  const int* dstI = ei + E;

  char* w = (char*)d_ws;
  auto alloc = [&](size_t bytes)->char*{
    char* p = w;
    w += (bytes + 255) & ~(size_t)255;
    return p;
  };
  u16* Ha    = (u16*)alloc((size_t)N*256*2);
  u16* Hb    = (u16*)alloc((size_t)N*256*2);
  u16* linT  = (u16*)alloc((size_t)256*Gpad*2);
  u16* w1T   = (u16*)alloc(256*256*2);
  u16* w2T   = (u16*)alloc(256*256*2);
  u16* w3T   = (u16*)alloc(256*256*2);
  int* cnt    = (int*)alloc((size_t)N*4);
  int* cursor = (int*)alloc((size_t)N*4);
  int* rowp   = (int*)alloc((size_t)(N+1)*4);
  int* colx   = (int*)alloc((size_t)E*4);
  float* dinv = (float*)alloc((size_t)N*4);
  int* bsum   = (int*)alloc(1024);
  int* boff   = (int*)alloc(1024);
  float* bnsum= (float*)alloc(1024);
  float* bnsq = (float*)alloc(1024);
  float* scl  = (float*)alloc(1024);
  float* shf  = (float*)alloc(1024);

  hipMemsetAsync(cnt,    0, (size_t)N*4, stream);
  hipMemsetAsync(cursor, 0, (size_t)N*4, stream);
  hipMemsetAsync(bnsum,  0, 2048, stream);               // bnsum + bnsq (contiguous)

  const int NB = (N + 255)/256;

  transpose_weights<<<dim3(8, Gpad>>5, 4), 256, 0, stream>>>(
      lin_w, c1w, c2w, m1w, linT, w1T, w2T, w3T, G, Gpad);
  count_kernel  <<<dim3((E+255)/256), 256, 0, stream>>>(dstI, cnt, E);
  scan_reduce   <<<dim3(NB), 256, 0, stream>>>(cnt, bsum, N);
  scan_offsets  <<<dim3(1),  256, 0, stream>>>(bsum, boff, NB);
  scan_final    <<<dim3(NB), 256, 0, stream>>>(cnt, boff, rowp, dinv, N, E);
  scatter_kernel<<<dim3((E+255)/256), 256, 0, stream>>>(srcI, dstI, rowp, cursor, colx, E);

  dim3 ggrid(2, (N+127)/128);
  gemm_async<true,  false><<<ggrid, 256, 0, stream>>>(x,  G,   G,   linT, Gpad, Ha, nullptr, N);
  gemm_async<false, false><<<ggrid, 256, 0, stream>>>(Ha, 256, 256, w1T,  256,  Hb, nullptr, N);
  agg_kernel<<<dim3((N+3)/4), 256, 0, stream>>>(Hb, c1b, dinv, rowp, colx, Ha, N);
  gemm_async<false, false><<<ggrid, 256, 0, stream>>>(Ha, 256, 256, w2T,  256,  Hb, nullptr, N);
  agg_kernel<<<dim3((N+3)/4), 256, 0, stream>>>(Hb, c2b, dinv, rowp, colx, Ha, N);
  gemm_async<false, true ><<<ggrid, 256, 0, stream>>>(Ha, 256, 256, w3T,  256,  Hb, m1b, N);
  bn_stats   <<<dim3(256), 256, 0, stream>>>(Hb, bnsum, bnsq, N);
  bn_finalize<<<dim3(1),   256, 0, stream>>>(bnsum, bnsq, gam, bet, scl, shf, N);
  final_kernel<<<dim3(NB), 256, 0, stream>>>(Hb, scl, shf, m2w, m2b, out, N);
}